// Round 5
// baseline (2141.555 us; speedup 1.0000x reference)
//
#include <hip/hip_runtime.h>
#include <math.h>

typedef _Float16 f16;
typedef _Float16 f16x8 __attribute__((ext_vector_type(8)));
typedef float    f32x4 __attribute__((ext_vector_type(4)));

#define NBLK 256
#define NTHR 512
#define MROW 64

// fragment regions in d_ws (1 frag = 512 fp16 = 1KB; lane l holds 8 fp16 at l*8)
// B-frag for v_mfma_f32_16x16x32_f16: lane l -> col j = jb + (l&15), k = kb + (l>>4)*8 + jj
#define DEC_F 0      // (jf<<5 | st<<3 | kc)           jf 0..15, st 0..3, kc 0..7
#define FC1_F 512    // 512 + jf*8 + kc
#define FC2_F 640    // 640 + kc
#define ENC_F 648    // 648 + jf*36 + (x: kc*3+st | 12 + kc*3+st)
#define TOT_F 1224
#define TOT_E (TOT_F*512)   // 626,688 fp16 = 1.25 MB

__device__ __forceinline__ float sigm(float v){
  return __fdividef(1.0f, 1.0f + __expf(-v));
}
__device__ __forceinline__ float tanh_f(float v){
  float t = fminf(v, 8.0f);
  float e = __expf(2.0f * t);
  return 1.0f - 2.0f * __fdividef(1.0f, e + 1.0f);
}
// LDS element index with XOR swizzle (k bits [3:5] ^ row&7)
__device__ __forceinline__ int eH(int row, int k){ return row*256 + (k ^ ((row & 7) << 3)); }
__device__ __forceinline__ int eX(int row, int k){ return row*128 + (k ^ ((row & 7) << 3)); }

// ---------------- prep: pack all weights as fp16 B-fragments (validated r2-r4) ----------------
__global__ void prep_pack(const float* __restrict__ eWih, const float* __restrict__ eWhh,
                          const float* __restrict__ dWih, const float* __restrict__ dWhh,
                          const float* __restrict__ f1W,  const float* __restrict__ f2W,
                          f16* __restrict__ ws16)
{
  int idx = blockIdx.x * 256 + threadIdx.x;
  if (idx >= TOT_E) return;
  int frag = idx >> 9;
  int lo   = idx & 511;
  int l    = lo >> 3;
  int jj   = lo & 7;
  int c16  = l & 15;
  int q    = l >> 4;
  float v = 0.0f;
  if (frag < FC1_F){                       // decoder GRU
    int jf = frag >> 5, st = (frag >> 3) & 3, kc = frag & 7;
    int j = jf*16 + c16, k = kc*32 + q*8 + jj;
    if      (st == 0) v = dWih[j*256 + k]        + dWhh[j*256 + k];          // r (presummed)
    else if (st == 1) v = dWih[(256+j)*256 + k]  + dWhh[(256+j)*256 + k];    // z (presummed)
    else if (st == 2) v = dWih[(512+j)*256 + k];                             // in
    else              v = dWhh[(512+j)*256 + k];                             // hn
  } else if (frag < FC2_F){                // fc1
    int f = frag - FC1_F, jf = f >> 3, kc = f & 7;
    int j = jf*16 + c16, k = kc*32 + q*8 + jj;
    v = f1W[j*256 + k];
  } else if (frag < ENC_F){                // fc2 (cols >=2 zero-padded)
    int kc = frag - FC2_F;
    int j = c16, k = kc*32 + q*8 + jj;
    v = (j < 2) ? f2W[j*256 + k] : 0.0f;
  } else {                                 // encoder GRU
    int f = frag - ENC_F, jf = f / 36, r = f % 36;
    int j = jf*16 + c16;
    if (r < 12){ int kc = r/3, st = r%3; int k = kc*32 + q*8 + jj;
      v = eWih[(st*256 + j)*128 + k]; }
    else { r -= 12; int kc = r/3, st = r%3; int k = kc*32 + q*8 + jj;
      v = eWhh[(st*256 + j)*256 + k]; }
  }
  ws16[idx] = (f16)v;
}

// ---------------- fused persistent kernel ----------------
// launch_bounds(512, 1): 1 block/CU resident, 2 waves/SIMD, 256-reg cap per thread.
__global__ __launch_bounds__(NTHR, 1)
void fused_net(const float* __restrict__ x,
               const float* __restrict__ emW, const float* __restrict__ emb_,
               const float* __restrict__ evW, const float* __restrict__ evb,
               const float* __restrict__ ebih, const float* __restrict__ ebhh,
               const float* __restrict__ dbih, const float* __restrict__ dbhh,
               const float* __restrict__ f1b, const float* __restrict__ f2b,
               const f16* __restrict__ ws16, float* __restrict__ out)
{
  __shared__ __align__(16) f16 hA[16384];   // [64][256] fp16, swizzled
  __shared__ __align__(16) f16 hB[16384];
  __shared__ __align__(16) f16 hC[16384];   // fc1-out (decoder); xb [64][128] (encoder)

  const int tid = threadIdx.x;
  const int r0  = blockIdx.x * MROW;
  const int l   = tid & 63;
  const int w   = tid >> 6;        // wave 0..7
  const int c16 = l & 15;
  const int q   = l >> 4;
  const int swm = (c16 & 7) << 3;  // per-lane swizzle mask

  f16* hp = hA;
  f16* hq = hB;
  f16* xb = hC;

  int aoff[8], xoff[4];
  #pragma unroll
  for (int kc = 0; kc < 8; ++kc) aoff[kc] = c16*256 + ((kc*32 + q*8) ^ swm);
  #pragma unroll
  for (int kc = 0; kc < 4; ++kc) xoff[kc] = c16*128 + ((kc*32 + q*8) ^ swm);

  // weight-region base pointers for this wave (col-frags 2w, 2w+1)
  const f16* wpe0 = ws16 + (size_t)(ENC_F + (2*w    )*36)*512 + l*8;
  const f16* wpe1 = ws16 + (size_t)(ENC_F + (2*w + 1)*36)*512 + l*8;
  const f16* wpd0 = ws16 + (size_t)((2*w    )*32)*512 + l*8;
  const f16* wpd1 = ws16 + (size_t)((2*w + 1)*32)*512 + l*8;
  const f16* wp1  = ws16 + (size_t)(FC1_F + (2*w)*8)*512 + l*8;
  const f16* wp2  = ws16 + (size_t)FC2_F*512 + l*8;

  // early-issue encoder jf0 x-part burst (no dependencies)
  f16x8 ex[12];
  #pragma unroll
  for (int i = 0; i < 12; ++i) ex[i] = *(const f16x8*)(wpe0 + i*512);

  for (int i = tid; i < 16384; i += NTHR) hA[i] = (f16)0.0f;   // h0 = 0
  __syncthreads();

  // =============== ENCODER: 9 GRU steps ===============
  #pragma unroll 1
  for (int t = 0; t < 9; ++t){
    { // xt = tanh(embedding) -> xb
      int e  = tid & 127;
      int rq = tid >> 7;                      // 0..3 -> rows rq*16..+15
      const float* Wp = (t < 8) ? (evW + e*6) : (emW + e*6);
      float bb = (t < 8) ? evb[e] : emb_[e];
      float w0 = Wp[0], w1 = Wp[1], w2 = Wp[2], w3 = Wp[3], w4 = Wp[4], w5 = Wp[5];
      int xo = (t < 8) ? (6 + t*6) : 0;
      #pragma unroll 1
      for (int rr = 0; rr < 16; ++rr){
        int row = rq*16 + rr;
        const float* xs = x + (size_t)(r0 + row)*54 + xo;
        float a = bb + xs[0]*w0 + xs[1]*w1 + xs[2]*w2 + xs[3]*w3 + xs[4]*w4 + xs[5]*w5;
        xb[eX(row, e)] = (f16)tanh_f(a);
      }
    }
    __syncthreads();

    // ---- jfi = 0 (col-frag jf = 2w), ex already in flight ----
    f16x8 ex1[12];
    {
      f16x8 eh[24];
      #pragma unroll
      for (int i = 0; i < 24; ++i) eh[i] = *(const f16x8*)(wpe0 + (12 + i)*512);

      f32x4 ar[4], az[4], an[4], ah[4];
      #pragma unroll
      for (int rf = 0; rf < 4; ++rf){ ar[rf] = 0.f; az[rf] = 0.f; an[rf] = 0.f; ah[rf] = 0.f; }

      #pragma unroll
      for (int kc = 0; kc < 4; ++kc){
        f16x8 av[4];
        #pragma unroll
        for (int rf = 0; rf < 4; ++rf) av[rf] = *(const f16x8*)(xb + xoff[kc] + rf*2048);
        #pragma unroll
        for (int rf = 0; rf < 4; ++rf){
          ar[rf] = __builtin_amdgcn_mfma_f32_16x16x32_f16(av[rf], ex[kc*3+0], ar[rf], 0, 0, 0);
          az[rf] = __builtin_amdgcn_mfma_f32_16x16x32_f16(av[rf], ex[kc*3+1], az[rf], 0, 0, 0);
          an[rf] = __builtin_amdgcn_mfma_f32_16x16x32_f16(av[rf], ex[kc*3+2], an[rf], 0, 0, 0);
        }
      }
      #pragma unroll
      for (int kc = 0; kc < 8; ++kc){
        f16x8 av[4];
        #pragma unroll
        for (int rf = 0; rf < 4; ++rf) av[rf] = *(const f16x8*)(hp + aoff[kc] + rf*4096);
        #pragma unroll
        for (int rf = 0; rf < 4; ++rf){
          ar[rf] = __builtin_amdgcn_mfma_f32_16x16x32_f16(av[rf], eh[kc*3+0], ar[rf], 0, 0, 0);
          az[rf] = __builtin_amdgcn_mfma_f32_16x16x32_f16(av[rf], eh[kc*3+1], az[rf], 0, 0, 0);
          ah[rf] = __builtin_amdgcn_mfma_f32_16x16x32_f16(av[rf], eh[kc*3+2], ah[rf], 0, 0, 0);
        }
      }
      // prefetch jf1 x-part (hides under epilogue)
      #pragma unroll
      for (int i = 0; i < 12; ++i) ex1[i] = *(const f16x8*)(wpe1 + i*512);

      int j = (2*w)*16 + c16;
      float br = ebih[j]       + ebhh[j];
      float bz = ebih[256 + j] + ebhh[256 + j];
      float bi = ebih[512 + j];
      float bh = ebhh[512 + j];
      #pragma unroll
      for (int rf = 0; rf < 4; ++rf){
        #pragma unroll
        for (int r = 0; r < 4; ++r){
          int row = rf*16 + q*4 + r;
          float rv = sigm(ar[rf][r] + br);
          float zv = sigm(az[rf][r] + bz);
          float nv = tanh_f(an[rf][r] + bi + rv*(ah[rf][r] + bh));
          float ho = (float)hp[eH(row, j)];
          hq[eH(row, j)] = (f16)(nv + zv*(ho - nv));
        }
      }
    }
    // ---- jfi = 1 (col-frag jf = 2w+1) ----
    {
      f16x8 eh[24];
      #pragma unroll
      for (int i = 0; i < 24; ++i) eh[i] = *(const f16x8*)(wpe1 + (12 + i)*512);

      f32x4 ar[4], az[4], an[4], ah[4];
      #pragma unroll
      for (int rf = 0; rf < 4; ++rf){ ar[rf] = 0.f; az[rf] = 0.f; an[rf] = 0.f; ah[rf] = 0.f; }

      #pragma unroll
      for (int kc = 0; kc < 4; ++kc){
        f16x8 av[4];
        #pragma unroll
        for (int rf = 0; rf < 4; ++rf) av[rf] = *(const f16x8*)(xb + xoff[kc] + rf*2048);
        #pragma unroll
        for (int rf = 0; rf < 4; ++rf){
          ar[rf] = __builtin_amdgcn_mfma_f32_16x16x32_f16(av[rf], ex1[kc*3+0], ar[rf], 0, 0, 0);
          az[rf] = __builtin_amdgcn_mfma_f32_16x16x32_f16(av[rf], ex1[kc*3+1], az[rf], 0, 0, 0);
          an[rf] = __builtin_amdgcn_mfma_f32_16x16x32_f16(av[rf], ex1[kc*3+2], an[rf], 0, 0, 0);
        }
      }
      #pragma unroll
      for (int kc = 0; kc < 8; ++kc){
        f16x8 av[4];
        #pragma unroll
        for (int rf = 0; rf < 4; ++rf) av[rf] = *(const f16x8*)(hp + aoff[kc] + rf*4096);
        #pragma unroll
        for (int rf = 0; rf < 4; ++rf){
          ar[rf] = __builtin_amdgcn_mfma_f32_16x16x32_f16(av[rf], eh[kc*3+0], ar[rf], 0, 0, 0);
          az[rf] = __builtin_amdgcn_mfma_f32_16x16x32_f16(av[rf], eh[kc*3+1], az[rf], 0, 0, 0);
          ah[rf] = __builtin_amdgcn_mfma_f32_16x16x32_f16(av[rf], eh[kc*3+2], ah[rf], 0, 0, 0);
        }
      }
      // prefetch next t's jf0 x-part (hides under epilogue)
      if (t < 8){
        #pragma unroll
        for (int i = 0; i < 12; ++i) ex[i] = *(const f16x8*)(wpe0 + i*512);
      }

      int j = (2*w + 1)*16 + c16;
      float br = ebih[j]       + ebhh[j];
      float bz = ebih[256 + j] + ebhh[256 + j];
      float bi = ebih[512 + j];
      float bh = ebhh[512 + j];
      #pragma unroll
      for (int rf = 0; rf < 4; ++rf){
        #pragma unroll
        for (int r = 0; r < 4; ++r){
          int row = rf*16 + q*4 + r;
          float rv = sigm(ar[rf][r] + br);
          float zv = sigm(az[rf][r] + bz);
          float nv = tanh_f(an[rf][r] + bi + rv*(ah[rf][r] + bh));
          float ho = (float)hp[eH(row, j)];
          hq[eH(row, j)] = (f16)(nv + zv*(ho - nv));
        }
      }
    }
    __syncthreads();
    { f16* tmp = hp; hp = hq; hq = tmp; }
  }

  // =============== DECODER: 32 x (GRU + fc1 + fc2) ===============
  // persistent per-lane decoder biases (11 regs)
  float dbr0, dbz0, dbi0, dbh0, dbr1, dbz1, dbi1, dbh1, f1b0, f1b1;
  {
    int j0 = (2*w)*16 + c16, j1 = (2*w + 1)*16 + c16;
    dbr0 = dbih[j0]       + dbhh[j0];
    dbz0 = dbih[256 + j0] + dbhh[256 + j0];
    dbi0 = dbih[512 + j0];
    dbh0 = dbhh[512 + j0];
    dbr1 = dbih[j1]       + dbhh[j1];
    dbz1 = dbih[256 + j1] + dbhh[256 + j1];
    dbi1 = dbih[512 + j1];
    dbh1 = dbhh[512 + j1];
    f1b0 = f1b[j0];
    f1b1 = f1b[j1];
  }
  const float f2bb = (c16 < 2) ? f2b[c16] : 0.0f;

  // prologue: issue jf0 GRU burst
  f16x8 bg[32];
  #pragma unroll
  for (int i = 0; i < 32; ++i) bg[i] = *(const f16x8*)(wpd0 + i*512);

  #pragma unroll 1
  for (int s = 0; s < 32; ++s){
    f16x8 bg1[32];
    // ---- GRU jfi0: reads hp, bg (in flight), writes hq cols of jf=2w ----
    {
      f32x4 ac[4][4];
      #pragma unroll
      for (int st = 0; st < 4; ++st)
        #pragma unroll
        for (int rf = 0; rf < 4; ++rf) ac[st][rf] = 0.f;

      #pragma unroll
      for (int kc = 0; kc < 8; ++kc){
        f16x8 av[4];
        #pragma unroll
        for (int rf = 0; rf < 4; ++rf) av[rf] = *(const f16x8*)(hp + aoff[kc] + rf*4096);
        #pragma unroll
        for (int st = 0; st < 4; ++st)
          #pragma unroll
          for (int rf = 0; rf < 4; ++rf)
            ac[st][rf] = __builtin_amdgcn_mfma_f32_16x16x32_f16(av[rf], bg[st*8+kc], ac[st][rf], 0, 0, 0);
      }
      // prefetch jf1 burst (hides under epilogue)
      #pragma unroll
      for (int i = 0; i < 32; ++i) bg1[i] = *(const f16x8*)(wpd1 + i*512);

      int j = (2*w)*16 + c16;
      #pragma unroll
      for (int rf = 0; rf < 4; ++rf){
        #pragma unroll
        for (int r = 0; r < 4; ++r){
          int row = rf*16 + q*4 + r;
          float rv = sigm(ac[0][rf][r] + dbr0);
          float zv = sigm(ac[1][rf][r] + dbz0);
          float nv = tanh_f(ac[2][rf][r] + dbi0 + rv*(ac[3][rf][r] + dbh0));
          float ho = (float)hp[eH(row, j)];
          hq[eH(row, j)] = (f16)(nv + zv*(ho - nv));
        }
      }
    }
    // ---- GRU jfi1 ----
    f16x8 bf1[16];
    {
      f32x4 ac[4][4];
      #pragma unroll
      for (int st = 0; st < 4; ++st)
        #pragma unroll
        for (int rf = 0; rf < 4; ++rf) ac[st][rf] = 0.f;

      #pragma unroll
      for (int kc = 0; kc < 8; ++kc){
        f16x8 av[4];
        #pragma unroll
        for (int rf = 0; rf < 4; ++rf) av[rf] = *(const f16x8*)(hp + aoff[kc] + rf*4096);
        #pragma unroll
        for (int st = 0; st < 4; ++st)
          #pragma unroll
          for (int rf = 0; rf < 4; ++rf)
            ac[st][rf] = __builtin_amdgcn_mfma_f32_16x16x32_f16(av[rf], bg1[st*8+kc], ac[st][rf], 0, 0, 0);
      }
      // prefetch FC1 burst (hides under epilogue)
      #pragma unroll
      for (int i = 0; i < 16; ++i) bf1[i] = *(const f16x8*)(wp1 + i*512);

      int j = (2*w + 1)*16 + c16;
      #pragma unroll
      for (int rf = 0; rf < 4; ++rf){
        #pragma unroll
        for (int r = 0; r < 4; ++r){
          int row = rf*16 + q*4 + r;
          float rv = sigm(ac[0][rf][r] + dbr1);
          float zv = sigm(ac[1][rf][r] + dbz1);
          float nv = tanh_f(ac[2][rf][r] + dbi1 + rv*(ac[3][rf][r] + dbh1));
          float ho = (float)hp[eH(row, j)];
          hq[eH(row, j)] = (f16)(nv + zv*(ho - nv));
        }
      }
    }
    __syncthreads();

    // ---- FC1: relu(h_new @ W1.T + b1): reads hq, writes -> hC ----
    f16x8 bf2[8];
    {
      f32x4 a1[2][4];
      #pragma unroll
      for (int jfi = 0; jfi < 2; ++jfi)
        #pragma unroll
        for (int rf = 0; rf < 4; ++rf) a1[jfi][rf] = 0.f;

      #pragma unroll
      for (int kc = 0; kc < 8; ++kc){
        f16x8 av[4];
        #pragma unroll
        for (int rf = 0; rf < 4; ++rf) av[rf] = *(const f16x8*)(hq + aoff[kc] + rf*4096);
        #pragma unroll
        for (int jfi = 0; jfi < 2; ++jfi)
          #pragma unroll
          for (int rf = 0; rf < 4; ++rf)
            a1[jfi][rf] = __builtin_amdgcn_mfma_f32_16x16x32_f16(av[rf], bf1[jfi*8+kc], a1[jfi][rf], 0, 0, 0);
      }
      // prefetch FC2 burst + next step's jf0 GRU burst (hide under epilogue + barrier)
      #pragma unroll
      for (int i = 0; i < 8; ++i) bf2[i] = *(const f16x8*)(wp2 + i*512);
      if (s < 31){
        #pragma unroll
        for (int i = 0; i < 32; ++i) bg[i] = *(const f16x8*)(wpd0 + i*512);
      }

      #pragma unroll
      for (int jfi = 0; jfi < 2; ++jfi){
        int j = (2*w + jfi)*16 + c16;
        float bb = jfi ? f1b1 : f1b0;
        #pragma unroll
        for (int rf = 0; rf < 4; ++rf)
          #pragma unroll
          for (int r = 0; r < 4; ++r){
            int row = rf*16 + q*4 + r;
            hC[eH(row, j)] = (f16)fmaxf(a1[jfi][rf][r] + bb, 0.0f);
          }
      }
    }
    __syncthreads();

    // ---- FC2 (waves 0-3, 16 rows each): y = tanh(hC @ W2.T + b2) -> out ----
    if (w < 4){
      f32x4 a2 = 0.f;
      #pragma unroll
      for (int kc = 0; kc < 8; ++kc){
        f16x8 av = *(const f16x8*)(hC + aoff[kc] + w*4096);
        a2 = __builtin_amdgcn_mfma_f32_16x16x32_f16(av, bf2[kc], a2, 0, 0, 0);
      }
      if (c16 < 2){
        #pragma unroll
        for (int r = 0; r < 4; ++r){
          int row = w*16 + q*4 + r;
          out[((size_t)(r0 + row)*32 + s)*2 + c16] = tanh_f(a2[r] + f2bb);
        }
      }
    }
    // no barrier: next GRU reads hp(unchanged)/writes hq(dead), FC2 reads hC — disjoint;
    // next FC1's hC write is after next GRU's barrier.
    { f16* tmp = hp; hp = hq; hq = tmp; }
  }
}

extern "C" void kernel_launch(void* const* d_in, const int* in_sizes, int n_in,
                              void* d_out, int out_size, void* d_ws, size_t ws_size,
                              hipStream_t stream)
{
  (void)in_sizes; (void)n_in; (void)out_size; (void)ws_size;
  const float* x    = (const float*)d_in[0];
  const float* emW  = (const float*)d_in[1];
  const float* emb_ = (const float*)d_in[2];
  const float* evW  = (const float*)d_in[3];
  const float* evb  = (const float*)d_in[4];
  const float* eWih = (const float*)d_in[5];
  const float* eWhh = (const float*)d_in[6];
  const float* ebih = (const float*)d_in[7];
  const float* ebhh = (const float*)d_in[8];
  const float* dWih = (const float*)d_in[9];
  const float* dWhh = (const float*)d_in[10];
  const float* dbih = (const float*)d_in[11];
  const float* dbhh = (const float*)d_in[12];
  const float* f1W  = (const float*)d_in[13];
  const float* f1b  = (const float*)d_in[14];
  const float* f2W  = (const float*)d_in[15];
  const float* f2b  = (const float*)d_in[16];
  float* out = (float*)d_out;
  f16* ws16 = (f16*)d_ws;

  prep_pack<<<(TOT_E + 255)/256, 256, 0, stream>>>(eWih, eWhh, dWih, dWhh, f1W, f2W, ws16);
  fused_net<<<NBLK, NTHR, 0, stream>>>(x, emW, emb_, evW, evb, ebih, ebhh,
                                       dbih, dbhh, f1b, f2b, ws16, out);
}

// Round 6
// 1406.856 us; speedup vs baseline: 1.5222x; 1.5222x over previous
//
#include <hip/hip_runtime.h>
#include <math.h>

typedef _Float16 f16;
typedef _Float16 f16x8 __attribute__((ext_vector_type(8)));
typedef float    f32x16 __attribute__((ext_vector_type(16)));

#define NBLK 256
#define NTHR 512
#define MROW 64

// ---- d_ws fragment layout (1 frag = 512 fp16 = 1KB) ----
// B-frag for v_mfma_f32_32x32x16_f16: lane l holds 8 fp16 at frag*512 + l*8:
//   col = ct*32 + (l&31), k = ks*16 + (l>>5)*8 + jj   (jj 0..7)
// dec GRU: frag = (ct*4 + st)*16 + ks          ct 0..7, st 0..3 (r,z,in,hn), ks 0..15
// fc1:     frag = 512 + ct*16 + ks
// fc2:     frag = 640 + ks                     (cols >=2 zero)
// enc GRU: frag = 656 + ct*72 + (x: st*8+ks [ks<8] | 24 + st*16+ks)  st 0..2
#define FC1_F 512
#define FC2_F 640
#define ENC_F 656
#define TOT_F 1232
#define TOT_E (TOT_F*512)   // 630,784 fp16 = 1.23 MB

__device__ __forceinline__ float sigm(float v){
  return __fdividef(1.0f, 1.0f + __expf(-v));
}
__device__ __forceinline__ float tanh_f(float v){
  float t = fminf(v, 8.0f);
  float e = __expf(2.0f * t);
  return 1.0f - 2.0f * __fdividef(1.0f, e + 1.0f);
}
// LDS element index, XOR swizzle on k bits [3:5] with row&7 (uniform banks for b128)
__device__ __forceinline__ int eH(int row, int k){ return row*256 + (k ^ ((row & 7) << 3)); }
__device__ __forceinline__ int eX(int row, int k){ return row*128 + (k ^ ((row & 7) << 3)); }

// ---------------- prep: pack weights as fp16 32x32x16 B-fragments ----------------
__global__ void prep_pack(const float* __restrict__ eWih, const float* __restrict__ eWhh,
                          const float* __restrict__ dWih, const float* __restrict__ dWhh,
                          const float* __restrict__ f1W,  const float* __restrict__ f2W,
                          f16* __restrict__ ws16)
{
  int idx = blockIdx.x * 256 + threadIdx.x;
  if (idx >= TOT_E) return;
  int frag = idx >> 9;
  int lo   = idx & 511;
  int l    = lo >> 3;
  int jj   = lo & 7;
  int c32  = l & 31;
  int half = l >> 5;
  int kin  = half*8 + jj;
  float v = 0.0f;
  if (frag < FC1_F){                       // decoder GRU
    int ct = frag >> 6, st = (frag >> 4) & 3, ks = frag & 15;
    int col = ct*32 + c32, k = ks*16 + kin;
    if      (st == 0) v = dWih[col*256 + k]        + dWhh[col*256 + k];        // r presummed
    else if (st == 1) v = dWih[(256+col)*256 + k]  + dWhh[(256+col)*256 + k];  // z presummed
    else if (st == 2) v = dWih[(512+col)*256 + k];                             // in
    else              v = dWhh[(512+col)*256 + k];                             // hn
  } else if (frag < FC2_F){                // fc1
    int f = frag - FC1_F, ct = f >> 4, ks = f & 15;
    int col = ct*32 + c32, k = ks*16 + kin;
    v = f1W[col*256 + k];
  } else if (frag < ENC_F){                // fc2 (cols >=2 zero)
    int ks = frag - FC2_F, k = ks*16 + kin;
    v = (c32 < 2) ? f2W[c32*256 + k] : 0.0f;
  } else {                                 // encoder GRU
    int f = frag - ENC_F, ct = f / 72, r = f % 72;
    int col = ct*32 + c32;
    if (r < 24){ int st = r >> 3, ks = r & 7;  v = eWih[(st*256 + col)*128 + ks*16 + kin]; }
    else { r -= 24; int st = r >> 4, ks = r & 15; v = eWhh[(st*256 + col)*256 + ks*16 + kin]; }
  }
  ws16[idx] = (f16)v;
}

// ---------------- fused persistent kernel ----------------
__global__ __launch_bounds__(NTHR, 1)
void fused_net(const float* __restrict__ x,
               const float* __restrict__ emW, const float* __restrict__ emb_,
               const float* __restrict__ evW, const float* __restrict__ evb,
               const float* __restrict__ ebih, const float* __restrict__ ebhh,
               const float* __restrict__ dbih, const float* __restrict__ dbhh,
               const float* __restrict__ f1b, const float* __restrict__ f2b,
               const f16* __restrict__ ws16, float* __restrict__ out)
{
  __shared__ __align__(16) f16 hA[16384];   // [64][256] fp16, swizzled
  __shared__ __align__(16) f16 hB[16384];
  __shared__ __align__(16) f16 hC[16384];   // xb [64][128] (encoder) / fc1-out (decoder)

  const int tid  = threadIdx.x;
  const int r0   = blockIdx.x * MROW;
  const int l    = tid & 63;
  const int w    = tid >> 6;        // wave 0..7 = col-tile ct
  const int c32  = l & 31;
  const int half = l >> 5;

  f16* hp = hA;
  f16* hq = hB;
  f16* xb = hC;

  // per-lane A-frag base element offset (row = c32, k-low bits swizzled)
  const int abase = c32*256 + ((half*8) ^ ((l & 7) << 3));   // stride-256 buffers
  const int xbase = c32*128 + ((half*8) ^ ((l & 7) << 3));   // stride-128 buffer
  const int colm  = w*32 + c32;                              // this lane's output column

  for (int i = tid; i < 16384; i += NTHR) hA[i] = (f16)0.0f; // h0 = 0
  __syncthreads();

  // weight-region base pointers (per lane)
  const f16* wdec = ws16 + (size_t)(w*64)*512 + (size_t)l*8;
  const f16* wfc1 = ws16 + (size_t)(FC1_F + w*16)*512 + (size_t)l*8;
  const f16* wfc2 = ws16 + (size_t)FC2_F*512 + (size_t)l*8;
  const f16* wenc = ws16 + (size_t)(ENC_F + w*72)*512 + (size_t)l*8;

  // =============== ENCODER: 9 GRU steps ===============
  {
    const float ebr = ebih[colm]       + ebhh[colm];
    const float ebz = ebih[256 + colm] + ebhh[256 + colm];
    const float ebn = ebih[512 + colm];
    const float ebh = ebhh[512 + colm];

    #pragma unroll 1
    for (int t = 0; t < 9; ++t){
      { // xt = tanh(embedding) -> xb
        int e  = tid & 127;
        int rq = tid >> 7;                      // 0..3 -> rows rq*16..+15
        const float* Wp = (t < 8) ? (evW + e*6) : (emW + e*6);
        float bb = (t < 8) ? evb[e] : emb_[e];
        float w0 = Wp[0], w1 = Wp[1], w2 = Wp[2], w3 = Wp[3], w4 = Wp[4], w5 = Wp[5];
        int xo = (t < 8) ? (6 + t*6) : 0;
        #pragma unroll 1
        for (int rr = 0; rr < 16; ++rr){
          int row = rq*16 + rr;
          const float* xs = x + (size_t)(r0 + row)*54 + xo;
          float a = bb + xs[0]*w0 + xs[1]*w1 + xs[2]*w2 + xs[3]*w3 + xs[4]*w4 + xs[5]*w5;
          xb[eX(row, e)] = (f16)tanh_f(a);
        }
      }
      __syncthreads();

      f32x16 aR[2], aZ[2], aN[2], aH[2];
      #pragma unroll
      for (int rt = 0; rt < 2; ++rt){ aR[rt] = 0.f; aZ[rt] = 0.f; aN[rt] = 0.f; aH[rt] = 0.f; }

      // x-part: K=128 (ks 0..7), streams r,z,in
      {
        f16x8 b0 = *(const f16x8*)(wenc + (0*8 + 0)*512);
        f16x8 b1 = *(const f16x8*)(wenc + (1*8 + 0)*512);
        f16x8 b2 = *(const f16x8*)(wenc + (2*8 + 0)*512);
        #pragma unroll
        for (int ks = 0; ks < 8; ++ks){
          f16x8 n0, n1, n2;
          if (ks < 7){
            n0 = *(const f16x8*)(wenc + (0*8 + ks + 1)*512);
            n1 = *(const f16x8*)(wenc + (1*8 + ks + 1)*512);
            n2 = *(const f16x8*)(wenc + (2*8 + ks + 1)*512);
          }
          f16x8 a0 = *(const f16x8*)(xb + ((xbase       ) ^ (ks*16)));
          f16x8 a1 = *(const f16x8*)(xb + ((xbase + 4096) ^ (ks*16)));
          aR[0] = __builtin_amdgcn_mfma_f32_32x32x16_f16(a0, b0, aR[0], 0, 0, 0);
          aR[1] = __builtin_amdgcn_mfma_f32_32x32x16_f16(a1, b0, aR[1], 0, 0, 0);
          aZ[0] = __builtin_amdgcn_mfma_f32_32x32x16_f16(a0, b1, aZ[0], 0, 0, 0);
          aZ[1] = __builtin_amdgcn_mfma_f32_32x32x16_f16(a1, b1, aZ[1], 0, 0, 0);
          aN[0] = __builtin_amdgcn_mfma_f32_32x32x16_f16(a0, b2, aN[0], 0, 0, 0);
          aN[1] = __builtin_amdgcn_mfma_f32_32x32x16_f16(a1, b2, aN[1], 0, 0, 0);
          if (ks < 7){ b0 = n0; b1 = n1; b2 = n2; }
        }
      }
      // h-part: K=256 (ks 0..15), streams r,z,hn
      {
        f16x8 b0 = *(const f16x8*)(wenc + (24 + 0*16 + 0)*512);
        f16x8 b1 = *(const f16x8*)(wenc + (24 + 1*16 + 0)*512);
        f16x8 b2 = *(const f16x8*)(wenc + (24 + 2*16 + 0)*512);
        #pragma unroll
        for (int ks = 0; ks < 16; ++ks){
          f16x8 n0, n1, n2;
          if (ks < 15){
            n0 = *(const f16x8*)(wenc + (24 + 0*16 + ks + 1)*512);
            n1 = *(const f16x8*)(wenc + (24 + 1*16 + ks + 1)*512);
            n2 = *(const f16x8*)(wenc + (24 + 2*16 + ks + 1)*512);
          }
          f16x8 a0 = *(const f16x8*)(hp + ((abase       ) ^ (ks*16)));
          f16x8 a1 = *(const f16x8*)(hp + ((abase + 8192) ^ (ks*16)));
          aR[0] = __builtin_amdgcn_mfma_f32_32x32x16_f16(a0, b0, aR[0], 0, 0, 0);
          aR[1] = __builtin_amdgcn_mfma_f32_32x32x16_f16(a1, b0, aR[1], 0, 0, 0);
          aZ[0] = __builtin_amdgcn_mfma_f32_32x32x16_f16(a0, b1, aZ[0], 0, 0, 0);
          aZ[1] = __builtin_amdgcn_mfma_f32_32x32x16_f16(a1, b1, aZ[1], 0, 0, 0);
          aH[0] = __builtin_amdgcn_mfma_f32_32x32x16_f16(a0, b2, aH[0], 0, 0, 0);
          aH[1] = __builtin_amdgcn_mfma_f32_32x32x16_f16(a1, b2, aH[1], 0, 0, 0);
          if (ks < 15){ b0 = n0; b1 = n1; b2 = n2; }
        }
      }
      // epilogue
      #pragma unroll
      for (int rt = 0; rt < 2; ++rt){
        #pragma unroll
        for (int rg = 0; rg < 16; ++rg){
          int rr  = (rg & 3) + 8*(rg >> 2) + 4*half;
          int row = rt*32 + rr;
          int el  = row*256 + (colm ^ ((rr & 7) << 3));
          float rv = sigm(aR[rt][rg] + ebr);
          float zv = sigm(aZ[rt][rg] + ebz);
          float nv = tanh_f(aN[rt][rg] + ebn + rv*(aH[rt][rg] + ebh));
          float ho = (float)hp[el];
          hq[el] = (f16)(nv + zv*(ho - nv));
        }
      }
      __syncthreads();
      { f16* tmp = hp; hp = hq; hq = tmp; }
    }
  }

  // =============== DECODER: 32 x (GRU + fc1 + fc2) ===============
  const float dbr = dbih[colm]       + dbhh[colm];
  const float dbz = dbih[256 + colm] + dbhh[256 + colm];
  const float dbn = dbih[512 + colm];
  const float dbh = dbhh[512 + colm];
  const float f1bb = f1b[colm];
  const float f2bb = (c32 < 2) ? f2b[c32] : 0.0f;

  #pragma unroll 1
  for (int s = 0; s < 32; ++s){
    // ---- GRU: reads hp (+L2 weights), writes h_new -> hq ----
    {
      f32x16 aR[2], aZ[2], aN[2], aH[2];
      #pragma unroll
      for (int rt = 0; rt < 2; ++rt){ aR[rt] = 0.f; aZ[rt] = 0.f; aN[rt] = 0.f; aH[rt] = 0.f; }

      f16x8 b0 = *(const f16x8*)(wdec + (0*16 + 0)*512);
      f16x8 b1 = *(const f16x8*)(wdec + (1*16 + 0)*512);
      f16x8 b2 = *(const f16x8*)(wdec + (2*16 + 0)*512);
      f16x8 b3 = *(const f16x8*)(wdec + (3*16 + 0)*512);
      #pragma unroll
      for (int ks = 0; ks < 16; ++ks){
        f16x8 n0, n1, n2, n3;
        if (ks < 15){
          n0 = *(const f16x8*)(wdec + (0*16 + ks + 1)*512);
          n1 = *(const f16x8*)(wdec + (1*16 + ks + 1)*512);
          n2 = *(const f16x8*)(wdec + (2*16 + ks + 1)*512);
          n3 = *(const f16x8*)(wdec + (3*16 + ks + 1)*512);
        }
        f16x8 a0 = *(const f16x8*)(hp + ((abase       ) ^ (ks*16)));
        f16x8 a1 = *(const f16x8*)(hp + ((abase + 8192) ^ (ks*16)));
        aR[0] = __builtin_amdgcn_mfma_f32_32x32x16_f16(a0, b0, aR[0], 0, 0, 0);
        aR[1] = __builtin_amdgcn_mfma_f32_32x32x16_f16(a1, b0, aR[1], 0, 0, 0);
        aZ[0] = __builtin_amdgcn_mfma_f32_32x32x16_f16(a0, b1, aZ[0], 0, 0, 0);
        aZ[1] = __builtin_amdgcn_mfma_f32_32x32x16_f16(a1, b1, aZ[1], 0, 0, 0);
        aN[0] = __builtin_amdgcn_mfma_f32_32x32x16_f16(a0, b2, aN[0], 0, 0, 0);
        aN[1] = __builtin_amdgcn_mfma_f32_32x32x16_f16(a1, b2, aN[1], 0, 0, 0);
        aH[0] = __builtin_amdgcn_mfma_f32_32x32x16_f16(a0, b3, aH[0], 0, 0, 0);
        aH[1] = __builtin_amdgcn_mfma_f32_32x32x16_f16(a1, b3, aH[1], 0, 0, 0);
        if (ks < 15){ b0 = n0; b1 = n1; b2 = n2; b3 = n3; }
      }
      #pragma unroll
      for (int rt = 0; rt < 2; ++rt){
        #pragma unroll
        for (int rg = 0; rg < 16; ++rg){
          int rr  = (rg & 3) + 8*(rg >> 2) + 4*half;
          int row = rt*32 + rr;
          int el  = row*256 + (colm ^ ((rr & 7) << 3));
          float rv = sigm(aR[rt][rg] + dbr);
          float zv = sigm(aZ[rt][rg] + dbz);
          float nv = tanh_f(aN[rt][rg] + dbn + rv*(aH[rt][rg] + dbh));
          float ho = (float)hp[el];
          hq[el] = (f16)(nv + zv*(ho - nv));
        }
      }
    }
    __syncthreads();

    // ---- FC1: relu(h_new @ W1.T + b1): reads hq, writes -> hC ----
    {
      f32x16 aF[2];
      aF[0] = 0.f; aF[1] = 0.f;
      f16x8 b0 = *(const f16x8*)(wfc1 + 0*512);
      #pragma unroll
      for (int ks = 0; ks < 16; ++ks){
        f16x8 n0;
        if (ks < 15) n0 = *(const f16x8*)(wfc1 + (ks + 1)*512);
        f16x8 a0 = *(const f16x8*)(hq + ((abase       ) ^ (ks*16)));
        f16x8 a1 = *(const f16x8*)(hq + ((abase + 8192) ^ (ks*16)));
        aF[0] = __builtin_amdgcn_mfma_f32_32x32x16_f16(a0, b0, aF[0], 0, 0, 0);
        aF[1] = __builtin_amdgcn_mfma_f32_32x32x16_f16(a1, b0, aF[1], 0, 0, 0);
        if (ks < 15) b0 = n0;
      }
      #pragma unroll
      for (int rt = 0; rt < 2; ++rt){
        #pragma unroll
        for (int rg = 0; rg < 16; ++rg){
          int rr  = (rg & 3) + 8*(rg >> 2) + 4*half;
          int row = rt*32 + rr;
          int el  = row*256 + (colm ^ ((rr & 7) << 3));
          hC[el] = (f16)fmaxf(aF[rt][rg] + f1bb, 0.0f);
        }
      }
    }
    __syncthreads();

    // ---- FC2 (waves 0-1, one 32-row tile each): y = tanh(hC @ W2.T + b2) -> out ----
    if (w < 2){
      f32x16 a2 = 0.f;
      f16x8 b0 = *(const f16x8*)(wfc2 + 0*512);
      #pragma unroll
      for (int ks = 0; ks < 16; ++ks){
        f16x8 n0;
        if (ks < 15) n0 = *(const f16x8*)(wfc2 + (ks + 1)*512);
        f16x8 a0 = *(const f16x8*)(hC + ((abase + w*8192) ^ (ks*16)));
        a2 = __builtin_amdgcn_mfma_f32_32x32x16_f16(a0, b0, a2, 0, 0, 0);
        if (ks < 15) b0 = n0;
      }
      if (c32 < 2){
        #pragma unroll
        for (int rg = 0; rg < 16; ++rg){
          int row = w*32 + (rg & 3) + 8*(rg >> 2) + 4*half;
          out[((size_t)(r0 + row)*32 + s)*2 + c32] = tanh_f(a2[rg] + f2bb);
        }
      }
    }
    // no barrier: next GRU reads hp(=h_new, pre-barrier)/writes hq(dead); FC2 reads hC — disjoint.
    { f16* tmp = hp; hp = hq; hq = tmp; }
  }
}

extern "C" void kernel_launch(void* const* d_in, const int* in_sizes, int n_in,
                              void* d_out, int out_size, void* d_ws, size_t ws_size,
                              hipStream_t stream)
{
  (void)in_sizes; (void)n_in; (void)out_size; (void)ws_size;
  const float* x    = (const float*)d_in[0];
  const float* emW  = (const float*)d_in[1];
  const float* emb_ = (const float*)d_in[2];
  const float* evW  = (const float*)d_in[3];
  const float* evb  = (const float*)d_in[4];
  const float* eWih = (const float*)d_in[5];
  const float* eWhh = (const float*)d_in[6];
  const float* ebih = (const float*)d_in[7];
  const float* ebhh = (const float*)d_in[8];
  const float* dWih = (const float*)d_in[9];
  const float* dWhh = (const float*)d_in[10];
  const float* dbih = (const float*)d_in[11];
  const float* dbhh = (const float*)d_in[12];
  const float* f1W  = (const float*)d_in[13];
  const float* f1b  = (const float*)d_in[14];
  const float* f2W  = (const float*)d_in[15];
  const float* f2b  = (const float*)d_in[16];
  float* out = (float*)d_out;
  f16* ws16 = (f16*)d_ws;

  prep_pack<<<(TOT_E + 255)/256, 256, 0, stream>>>(eWih, eWhh, dWih, dWhh, f1W, f2W, ws16);
  fused_net<<<NBLK, NTHR, 0, stream>>>(x, emW, emb_, evW, evb, ebih, ebhh,
                                       dbih, dbhh, f1b, f2b, ws16, out);
}

// Round 7
// 1290.775 us; speedup vs baseline: 1.6591x; 1.0899x over previous
//
#include <hip/hip_runtime.h>
#include <math.h>

typedef _Float16 f16;
typedef _Float16 f16x8 __attribute__((ext_vector_type(8)));
typedef float    f32x16 __attribute__((ext_vector_type(16)));

#define NBLK 256
#define NTHR 512
#define MROW 64

// ---- d_ws fragment layout (1 frag = 512 fp16 = 1KB) ---- (identical to r6, validated)
#define FC1_F 512
#define FC2_F 640
#define ENC_F 656
#define TOT_F 1232
#define TOT_E (TOT_F*512)

#define MFMA32(a,b,c) __builtin_amdgcn_mfma_f32_32x32x16_f16((a),(b),(c),0,0,0)

__device__ __forceinline__ float sigm(float v){
  return __fdividef(1.0f, 1.0f + __expf(-v));
}
__device__ __forceinline__ float tanh_f(float v){
  float t = fminf(v, 8.0f);
  float e = __expf(2.0f * t);
  return 1.0f - 2.0f * __fdividef(1.0f, e + 1.0f);
}
__device__ __forceinline__ int eH(int row, int k){ return row*256 + (k ^ ((row & 7) << 3)); }
__device__ __forceinline__ int eX(int row, int k){ return row*128 + (k ^ ((row & 7) << 3)); }

// ---------------- prep: pack weights as fp16 32x32x16 B-fragments (byte-identical to r6) ----------------
__global__ void prep_pack(const float* __restrict__ eWih, const float* __restrict__ eWhh,
                          const float* __restrict__ dWih, const float* __restrict__ dWhh,
                          const float* __restrict__ f1W,  const float* __restrict__ f2W,
                          f16* __restrict__ ws16)
{
  int idx = blockIdx.x * 256 + threadIdx.x;
  if (idx >= TOT_E) return;
  int frag = idx >> 9;
  int lo   = idx & 511;
  int l    = lo >> 3;
  int jj   = lo & 7;
  int c32  = l & 31;
  int half = l >> 5;
  int kin  = half*8 + jj;
  float v = 0.0f;
  if (frag < FC1_F){
    int ct = frag >> 6, st = (frag >> 4) & 3, ks = frag & 15;
    int col = ct*32 + c32, k = ks*16 + kin;
    if      (st == 0) v = dWih[col*256 + k]        + dWhh[col*256 + k];
    else if (st == 1) v = dWih[(256+col)*256 + k]  + dWhh[(256+col)*256 + k];
    else if (st == 2) v = dWih[(512+col)*256 + k];
    else              v = dWhh[(512+col)*256 + k];
  } else if (frag < FC2_F){
    int f = frag - FC1_F, ct = f >> 4, ks = f & 15;
    int col = ct*32 + c32, k = ks*16 + kin;
    v = f1W[col*256 + k];
  } else if (frag < ENC_F){
    int ks = frag - FC2_F, k = ks*16 + kin;
    v = (c32 < 2) ? f2W[c32*256 + k] : 0.0f;
  } else {
    int f = frag - ENC_F, ct = f / 72, r = f % 72;
    int col = ct*32 + c32;
    if (r < 24){ int st = r >> 3, ks = r & 7;  v = eWih[(st*256 + col)*128 + ks*16 + kin]; }
    else { r -= 24; int st = r >> 4, ks = r & 15; v = eWhh[(st*256 + col)*256 + ks*16 + kin]; }
  }
  ws16[idx] = (f16)v;
}

// ---------------- fused persistent kernel ----------------
__global__ __launch_bounds__(NTHR, 1)
void fused_net(const float* __restrict__ x,
               const float* __restrict__ emW, const float* __restrict__ emb_,
               const float* __restrict__ evW, const float* __restrict__ evb,
               const float* __restrict__ ebih, const float* __restrict__ ebhh,
               const float* __restrict__ dbih, const float* __restrict__ dbhh,
               const float* __restrict__ f1b, const float* __restrict__ f2b,
               const f16* __restrict__ ws16, float* __restrict__ out)
{
  __shared__ __align__(16) f16 hA[16384];
  __shared__ __align__(16) f16 hB[16384];
  __shared__ __align__(16) f16 hC[16384];   // xb (encoder) / fc1-out (decoder)

  const int tid  = threadIdx.x;
  const int r0   = blockIdx.x * MROW;
  const int l    = tid & 63;
  const int w    = tid >> 6;
  const int c32  = l & 31;
  const int half = l >> 5;

  f16* hp = hA;
  f16* hq = hB;
  f16* xb = hC;

  const int abase = c32*256 + ((half*8) ^ ((l & 7) << 3));
  const int xbase = c32*128 + ((half*8) ^ ((l & 7) << 3));
  const int colm  = w*32 + c32;

  for (int i = tid; i < 16384; i += NTHR) hA[i] = (f16)0.0f;
  __syncthreads();

  const f16* wdec = ws16 + (size_t)(w*64)*512 + (size_t)l*8;
  const f16* wfc1 = ws16 + (size_t)(FC1_F + w*16)*512 + (size_t)l*8;
  const f16* wfc2 = ws16 + (size_t)FC2_F*512 + (size_t)l*8;
  const f16* wenc = ws16 + (size_t)(ENC_F + w*72)*512 + (size_t)l*8;

  // =============== ENCODER: 9 GRU steps ===============
  {
    const float ebr = ebih[colm]       + ebhh[colm];
    const float ebz = ebih[256 + colm] + ebhh[256 + colm];
    const float ebn = ebih[512 + colm];
    const float ebh = ebhh[512 + colm];

    #pragma unroll 1
    for (int t = 0; t < 9; ++t){
      // issue x-phase (depth 2) and h-phase (depth 4) b-preloads; embed phase covers latency
      f16x8 bx[2][3], bh[4][3];
      #pragma unroll
      for (int p = 0; p < 2; ++p)
        #pragma unroll
        for (int st = 0; st < 3; ++st) bx[p][st] = *(const f16x8*)(wenc + (st*8 + p)*512);
      #pragma unroll
      for (int p = 0; p < 4; ++p)
        #pragma unroll
        for (int st = 0; st < 3; ++st) bh[p][st] = *(const f16x8*)(wenc + (24 + st*16 + p)*512);

      { // xt = tanh(embedding) -> xb
        int e  = tid & 127;
        int rq = tid >> 7;
        const float* Wp = (t < 8) ? (evW + e*6) : (emW + e*6);
        float bb = (t < 8) ? evb[e] : emb_[e];
        float w0 = Wp[0], w1 = Wp[1], w2 = Wp[2], w3 = Wp[3], w4 = Wp[4], w5 = Wp[5];
        int xo = (t < 8) ? (6 + t*6) : 0;
        #pragma unroll 1
        for (int rr = 0; rr < 16; ++rr){
          int row = rq*16 + rr;
          const float* xs = x + (size_t)(r0 + row)*54 + xo;
          float a = bb + xs[0]*w0 + xs[1]*w1 + xs[2]*w2 + xs[3]*w3 + xs[4]*w4 + xs[5]*w5;
          xb[eX(row, e)] = (f16)tanh_f(a);
        }
      }
      __syncthreads();

      f32x16 aR[2], aZ[2], aN[2], aH[2];
      #pragma unroll
      for (int rt = 0; rt < 2; ++rt){ aR[rt] = 0.f; aZ[rt] = 0.f; aN[rt] = 0.f; aH[rt] = 0.f; }

      // x-part: K=128 (ks 0..7), streams r,z,in — depth-2 rotation
      #pragma unroll
      for (int ks = 0; ks < 8; ++ks){
        f16x8 a0 = *(const f16x8*)(xb + ((xbase       ) ^ (ks*16)));
        f16x8 a1 = *(const f16x8*)(xb + ((xbase + 4096) ^ (ks*16)));
        aR[0] = MFMA32(a0, bx[ks&1][0], aR[0]);  aR[1] = MFMA32(a1, bx[ks&1][0], aR[1]);
        aZ[0] = MFMA32(a0, bx[ks&1][1], aZ[0]);  aZ[1] = MFMA32(a1, bx[ks&1][1], aZ[1]);
        aN[0] = MFMA32(a0, bx[ks&1][2], aN[0]);  aN[1] = MFMA32(a1, bx[ks&1][2], aN[1]);
        if (ks < 6){
          #pragma unroll
          for (int st = 0; st < 3; ++st)
            bx[ks&1][st] = *(const f16x8*)(wenc + (st*8 + ks + 2)*512);
        }
      }
      // h-part: K=256 (ks 0..15), streams r,z,hn — depth-4 rotation
      #pragma unroll
      for (int ks = 0; ks < 16; ++ks){
        f16x8 a0 = *(const f16x8*)(hp + ((abase       ) ^ (ks*16)));
        f16x8 a1 = *(const f16x8*)(hp + ((abase + 8192) ^ (ks*16)));
        aR[0] = MFMA32(a0, bh[ks&3][0], aR[0]);  aR[1] = MFMA32(a1, bh[ks&3][0], aR[1]);
        aZ[0] = MFMA32(a0, bh[ks&3][1], aZ[0]);  aZ[1] = MFMA32(a1, bh[ks&3][1], aZ[1]);
        aH[0] = MFMA32(a0, bh[ks&3][2], aH[0]);  aH[1] = MFMA32(a1, bh[ks&3][2], aH[1]);
        if (ks < 12){
          #pragma unroll
          for (int st = 0; st < 3; ++st)
            bh[ks&3][st] = *(const f16x8*)(wenc + (24 + st*16 + ks + 4)*512);
        }
      }
      // epilogue
      #pragma unroll
      for (int rt = 0; rt < 2; ++rt){
        #pragma unroll
        for (int rg = 0; rg < 16; ++rg){
          int rr  = (rg & 3) + 8*(rg >> 2) + 4*half;
          int row = rt*32 + rr;
          int el  = row*256 + (colm ^ ((rr & 7) << 3));
          float rv = sigm(aR[rt][rg] + ebr);
          float zv = sigm(aZ[rt][rg] + ebz);
          float nv = tanh_f(aN[rt][rg] + ebn + rv*(aH[rt][rg] + ebh));
          float ho = (float)hp[el];
          hq[el] = (f16)(nv + zv*(ho - nv));
        }
      }
      __syncthreads();
      { f16* tmp = hp; hp = hq; hq = tmp; }
    }
  }

  // =============== DECODER: 32 x (GRU + fc1 + fc2) ===============
  const float dbr = dbih[colm]       + dbhh[colm];
  const float dbz = dbih[256 + colm] + dbhh[256 + colm];
  const float dbn = dbih[512 + colm];
  const float dbh = dbhh[512 + colm];
  const float f1bb = f1b[colm];
  const float f2bb = (c32 < 2) ? f2b[c32] : 0.0f;

  // prologue: GRU depth-3 pipe
  f16x8 bp[3][4];
  #pragma unroll
  for (int p = 0; p < 3; ++p)
    #pragma unroll
    for (int st = 0; st < 4; ++st) bp[p][st] = *(const f16x8*)(wdec + (st*16 + p)*512);

  #pragma unroll 1
  for (int s = 0; s < 32; ++s){
    // ---- GRU: reads hp, writes h_new -> hq ----
    f16x8 bp1[8];
    {
      f32x16 aR[2], aZ[2], aN[2], aH[2];
      #pragma unroll
      for (int rt = 0; rt < 2; ++rt){ aR[rt] = 0.f; aZ[rt] = 0.f; aN[rt] = 0.f; aH[rt] = 0.f; }

      #pragma unroll
      for (int ks = 0; ks < 16; ++ks){
        f16x8 a0 = *(const f16x8*)(hp + ((abase       ) ^ (ks*16)));
        f16x8 a1 = *(const f16x8*)(hp + ((abase + 8192) ^ (ks*16)));
        aR[0] = MFMA32(a0, bp[ks%3][0], aR[0]);  aR[1] = MFMA32(a1, bp[ks%3][0], aR[1]);
        aZ[0] = MFMA32(a0, bp[ks%3][1], aZ[0]);  aZ[1] = MFMA32(a1, bp[ks%3][1], aZ[1]);
        aN[0] = MFMA32(a0, bp[ks%3][2], aN[0]);  aN[1] = MFMA32(a1, bp[ks%3][2], aN[1]);
        aH[0] = MFMA32(a0, bp[ks%3][3], aH[0]);  aH[1] = MFMA32(a1, bp[ks%3][3], aH[1]);
        if (ks < 13){
          #pragma unroll
          for (int st = 0; st < 4; ++st)
            bp[ks%3][st] = *(const f16x8*)(wdec + (st*16 + ks + 3)*512);
        }
      }
      // issue FC1 depth-8 pipe now (bp dead; GRU epilogue + barrier cover latency)
      #pragma unroll
      for (int p = 0; p < 8; ++p) bp1[p] = *(const f16x8*)(wfc1 + p*512);

      #pragma unroll
      for (int rt = 0; rt < 2; ++rt){
        #pragma unroll
        for (int rg = 0; rg < 16; ++rg){
          int rr  = (rg & 3) + 8*(rg >> 2) + 4*half;
          int row = rt*32 + rr;
          int el  = row*256 + (colm ^ ((rr & 7) << 3));
          float rv = sigm(aR[rt][rg] + dbr);
          float zv = sigm(aZ[rt][rg] + dbz);
          float nv = tanh_f(aN[rt][rg] + dbn + rv*(aH[rt][rg] + dbh));
          float ho = (float)hp[el];
          hq[el] = (f16)(nv + zv*(ho - nv));
        }
      }
    }
    __syncthreads();

    // ---- FC1: relu(h_new @ W1.T + b1): reads hq, writes -> hC ----
    f16x8 bp2[4];
    {
      f32x16 aF[2];
      aF[0] = 0.f; aF[1] = 0.f;
      #pragma unroll
      for (int ks = 0; ks < 16; ++ks){
        f16x8 a0 = *(const f16x8*)(hq + ((abase       ) ^ (ks*16)));
        f16x8 a1 = *(const f16x8*)(hq + ((abase + 8192) ^ (ks*16)));
        aF[0] = MFMA32(a0, bp1[ks&7], aF[0]);
        aF[1] = MFMA32(a1, bp1[ks&7], aF[1]);
        if (ks < 8) bp1[ks&7] = *(const f16x8*)(wfc1 + (ks + 8)*512);
      }
      // issue next step's GRU depth-3 pipe + FC2 depth-4 pipe (FC1 epilogue + barrier cover)
      if (s < 31){
        #pragma unroll
        for (int p = 0; p < 3; ++p)
          #pragma unroll
          for (int st = 0; st < 4; ++st) bp[p][st] = *(const f16x8*)(wdec + (st*16 + p)*512);
      }
      if (w < 2){
        #pragma unroll
        for (int p = 0; p < 4; ++p) bp2[p] = *(const f16x8*)(wfc2 + p*512);
      }

      #pragma unroll
      for (int rt = 0; rt < 2; ++rt){
        #pragma unroll
        for (int rg = 0; rg < 16; ++rg){
          int rr  = (rg & 3) + 8*(rg >> 2) + 4*half;
          int row = rt*32 + rr;
          int el  = row*256 + (colm ^ ((rr & 7) << 3));
          hC[el] = (f16)fmaxf(aF[rt][rg] + f1bb, 0.0f);
        }
      }
    }
    __syncthreads();

    // ---- FC2 (waves 0-1): y = tanh(hC @ W2.T + b2) -> out; overlaps next GRU on waves 2-7 ----
    if (w < 2){
      f32x16 a2 = 0.f;
      #pragma unroll
      for (int ks = 0; ks < 16; ++ks){
        f16x8 a0 = *(const f16x8*)(hC + ((abase + w*8192) ^ (ks*16)));
        a2 = MFMA32(a0, bp2[ks&3], a2);
        if (ks < 12) bp2[ks&3] = *(const f16x8*)(wfc2 + (ks + 4)*512);
      }
      if (c32 < 2){
        #pragma unroll
        for (int rg = 0; rg < 16; ++rg){
          int row = w*32 + (rg & 3) + 8*(rg >> 2) + 4*half;
          out[((size_t)(r0 + row)*32 + s)*2 + c32] = tanh_f(a2[rg] + f2bb);
        }
      }
    }
    // no barrier: next GRU reads hp(=h_new)/writes hq(dead); FC2 reads hC — disjoint.
    { f16* tmp = hp; hp = hq; hq = tmp; }
  }
}

extern "C" void kernel_launch(void* const* d_in, const int* in_sizes, int n_in,
                              void* d_out, int out_size, void* d_ws, size_t ws_size,
                              hipStream_t stream)
{
  (void)in_sizes; (void)n_in; (void)out_size; (void)ws_size;
  const float* x    = (const float*)d_in[0];
  const float* emW  = (const float*)d_in[1];
  const float* emb_ = (const float*)d_in[2];
  const float* evW  = (const float*)d_in[3];
  const float* evb  = (const float*)d_in[4];
  const float* eWih = (const float*)d_in[5];
  const float* eWhh = (const float*)d_in[6];
  const float* ebih = (const float*)d_in[7];
  const float* ebhh = (const float*)d_in[8];
  const float* dWih = (const float*)d_in[9];
  const float* dWhh = (const float*)d_in[10];
  const float* dbih = (const float*)d_in[11];
  const float* dbhh = (const float*)d_in[12];
  const float* f1W  = (const float*)d_in[13];
  const float* f1b  = (const float*)d_in[14];
  const float* f2W  = (const float*)d_in[15];
  const float* f2b  = (const float*)d_in[16];
  float* out = (float*)d_out;
  f16* ws16 = (f16*)d_ws;

  prep_pack<<<(TOT_E + 255)/256, 256, 0, stream>>>(eWih, eWhh, dWih, dWhh, f1W, f2W, ws16);
  fused_net<<<NBLK, NTHR, 0, stream>>>(x, emW, emb_, evW, evb, ebih, ebhh,
                                       dbih, dbhh, f1b, f2b, ws16, out);
}